// Round 1
// 107.309 us; speedup vs baseline: 1.0049x; 1.0049x over previous
//
#include <hip/hip_runtime.h>

#define NRAD 16
#define NCH  5
#define NMON 35
#define OUTW 144               // 16 + 4*32
#define ROWF (NRAD * NCH)      // 80 floats per edge row

// ---------------- Kernel A: segment offsets from sorted index ---------------
__global__ __launch_bounds__(256) void seg_offsets(
    const int* __restrict__ idx, int* __restrict__ seg, int E, int nat)
{
    int e = blockIdx.x * blockDim.x + threadIdx.x;
    if (e >= E) return;
    if (e == 0) {
        const int b = idx[0];
        for (int n = 0; n <= b; ++n) seg[n] = 0;
    } else {
        const int a = idx[e - 1], b = idx[e];
        for (int n = a + 1; n <= b; ++n) seg[n] = e;
    }
    if (e == E - 1) {
        const int a = idx[E - 1];
        for (int n = a + 1; n <= nat; ++n) seg[n] = E;
    }
}

// ---------------- edge inner body ------------------------------------------
__device__ __forceinline__ void edge_body(
    float x, float y, float z, float rad, float c4,
    float acc[NMON], float& acc2)
{
    const float x2 = x * x, x3 = x2 * x, x4 = x2 * x2;
    const float y2 = y * y, y3 = y2 * y, y4 = y2 * y2;
    const float z2 = z * z, z3 = z2 * z, z4 = z2 * z2;
    const float xy = x * y, xz = x * z, yz = y * z;

    acc2 += c4;
    acc[0]  += rad;
    acc[1]  = fmaf(rad, z,        acc[1]);
    acc[2]  = fmaf(rad, y,        acc[2]);
    acc[3]  = fmaf(rad, x,        acc[3]);
    acc[4]  = fmaf(rad, z2,       acc[4]);
    acc[5]  = fmaf(rad, yz,       acc[5]);
    acc[6]  = fmaf(rad, y2,       acc[6]);
    acc[7]  = fmaf(rad, xz,       acc[7]);
    acc[8]  = fmaf(rad, xy,       acc[8]);
    acc[9]  = fmaf(rad, x2,       acc[9]);
    acc[10] = fmaf(rad, z3,       acc[10]);
    acc[11] = fmaf(rad, y * z2,   acc[11]);
    acc[12] = fmaf(rad, y2 * z,   acc[12]);
    acc[13] = fmaf(rad, y3,       acc[13]);
    acc[14] = fmaf(rad, x * z2,   acc[14]);
    acc[15] = fmaf(rad, xy * z,   acc[15]);
    acc[16] = fmaf(rad, x * y2,   acc[16]);
    acc[17] = fmaf(rad, x2 * z,   acc[17]);
    acc[18] = fmaf(rad, x2 * y,   acc[18]);
    acc[19] = fmaf(rad, x3,       acc[19]);
    acc[20] = fmaf(rad, z4,       acc[20]);
    acc[21] = fmaf(rad, y * z3,   acc[21]);
    acc[22] = fmaf(rad, y2 * z2,  acc[22]);
    acc[23] = fmaf(rad, y3 * z,   acc[23]);
    acc[24] = fmaf(rad, y4,       acc[24]);
    acc[25] = fmaf(rad, x * z3,   acc[25]);
    acc[26] = fmaf(rad, xy * z2,  acc[26]);
    acc[27] = fmaf(rad, x * y2 * z, acc[27]);
    acc[28] = fmaf(rad, x * y3,   acc[28]);
    acc[29] = fmaf(rad, x2 * z2,  acc[29]);
    acc[30] = fmaf(rad, x2 * yz,  acc[30]);
    acc[31] = fmaf(rad, x2 * y2,  acc[31]);
    acc[32] = fmaf(rad, x3 * z,   acc[32]);
    acc[33] = fmaf(rad, x3 * y,   acc[33]);
    acc[34] = fmaf(rad, x4,       acc[34]);
}

// ---------------- Kernel B: ONE WAVE per atom, no LDS, no barriers ---------
// Each lane owns one (r, zi) channel; the wave streams its atom's edges
// directly from global. rad/c4 gathers fall inside one 320B row segment
// (coalesced); rij loads are wave-uniform broadcasts. Epilogue is lane-local.
__global__ __launch_bounds__(64) void mbp_wave(
    const float* __restrict__ rij_unit,
    const float* __restrict__ radial_ij,
    const float* __restrict__ lambda_w,
    const float* __restrict__ fact_norm,
    const int*   __restrict__ seg,
    float* __restrict__ out)
{
    const int n    = blockIdx.x;
    const int lane = threadIdx.x;       // 64-thread block = 1 wave
    const int zi   = lane >> 4;
    const int r    = lane & 15;

    const int start = seg[n];
    const int end   = seg[n + 1];

    float acc[NMON];
    #pragma unroll
    for (int l = 0; l < NMON; ++l) acc[l] = 0.f;
    float acc2 = 0.f;

    const int off  = r * NCH + zi;      // channel 0..3 for this lane
    const int off4 = r * NCH + 4;       // two-body channel

    #pragma unroll 2
    for (int e = start; e < end; ++e) {
        const float* __restrict__ row = radial_ij + (size_t)e * ROWF;
        const float rad = row[off];
        const float c4  = row[off4];
        const float x   = rij_unit[3 * e + 0];
        const float y   = rij_unit[3 * e + 1];
        const float z   = rij_unit[3 * e + 2];
        edge_body(x, y, z, rad, c4, acc, acc2);
    }

    // ---------------- lane-local epilogue ----------------
    const float l0 = lambda_w[0], l1 = lambda_w[1];
    const float p0[5] = {1.f, l0, l0 * l0, l0 * l0 * l0, (l0 * l0) * (l0 * l0)};
    const float p1[5] = {1.f, l1, l1 * l1, l1 * l1 * l1, (l1 * l1) * (l1 * l1)};
    const int lsum_tab[NMON] = {0, 1,1,1, 2,2,2,2,2,2,
                                3,3,3,3,3,3,3,3,3,3,
                                4,4,4,4,4,4,4,4,4,4,4,4,4,4,4};
    float s0 = 0.f, s1 = 0.f;
    #pragma unroll
    for (int l = 0; l < NMON; ++l) {
        const float v  = acc[l] * fact_norm[l];
        const float v2 = v * v;
        s0 = fmaf(v2, p0[lsum_tab[l]], s0);
        s1 = fmaf(v2, p1[lsum_tab[l]], s1);
    }
    const float scale = 1.0f / (float)(1 << zi);   // 2^(1-zeta), zeta = zi+1
    float* orow = out + (long)n * OUTW;
    orow[16 + zi * 32 + r * 2 + 0] = s0 * scale;
    orow[16 + zi * 32 + r * 2 + 1] = s1 * scale;
    if (zi == 0) orow[r] = acc2;
}

extern "C" void kernel_launch(void* const* d_in, const int* in_sizes, int n_in,
                              void* d_out, int out_size, void* d_ws, size_t ws_size,
                              hipStream_t stream) {
    const float* rij_unit   = (const float*)d_in[0];
    const float* radial_ij  = (const float*)d_in[1];
    const float* lambda_w   = (const float*)d_in[2];
    const float* fact_norm  = (const float*)d_in[3];
    const int*   first_atom = (const int*)d_in[4];
    const int E   = in_sizes[4];
    const int nat = out_size / OUTW;

    int* seg = (int*)d_ws;   // nat+1 ints

    seg_offsets<<<(E + 255) / 256, 256, 0, stream>>>(first_atom, seg, E, nat);
    mbp_wave<<<nat, 64, 0, stream>>>(rij_unit, radial_ij, lambda_w,
                                     fact_norm, seg, (float*)d_out);
}

// Round 2
// 107.290 us; speedup vs baseline: 1.0051x; 1.0002x over previous
//
#include <hip/hip_runtime.h>

#define NRAD 16
#define NCH  5
#define NMON 35
#define OUTW 144               // 16 + 4*32
#define ROWF (NRAD * NCH)      // 80 floats per edge row

// ---------------- edge inner body ------------------------------------------
__device__ __forceinline__ void edge_body(
    float x, float y, float z, float rad, float c4,
    float acc[NMON], float& acc2)
{
    const float x2 = x * x, x3 = x2 * x, x4 = x2 * x2;
    const float y2 = y * y, y3 = y2 * y, y4 = y2 * y2;
    const float z2 = z * z, z3 = z2 * z, z4 = z2 * z2;
    const float xy = x * y, xz = x * z, yz = y * z;

    acc2 += c4;
    acc[0]  += rad;
    acc[1]  = fmaf(rad, z,        acc[1]);
    acc[2]  = fmaf(rad, y,        acc[2]);
    acc[3]  = fmaf(rad, x,        acc[3]);
    acc[4]  = fmaf(rad, z2,       acc[4]);
    acc[5]  = fmaf(rad, yz,       acc[5]);
    acc[6]  = fmaf(rad, y2,       acc[6]);
    acc[7]  = fmaf(rad, xz,       acc[7]);
    acc[8]  = fmaf(rad, xy,       acc[8]);
    acc[9]  = fmaf(rad, x2,       acc[9]);
    acc[10] = fmaf(rad, z3,       acc[10]);
    acc[11] = fmaf(rad, y * z2,   acc[11]);
    acc[12] = fmaf(rad, y2 * z,   acc[12]);
    acc[13] = fmaf(rad, y3,       acc[13]);
    acc[14] = fmaf(rad, x * z2,   acc[14]);
    acc[15] = fmaf(rad, xy * z,   acc[15]);
    acc[16] = fmaf(rad, x * y2,   acc[16]);
    acc[17] = fmaf(rad, x2 * z,   acc[17]);
    acc[18] = fmaf(rad, x2 * y,   acc[18]);
    acc[19] = fmaf(rad, x3,       acc[19]);
    acc[20] = fmaf(rad, z4,       acc[20]);
    acc[21] = fmaf(rad, y * z3,   acc[21]);
    acc[22] = fmaf(rad, y2 * z2,  acc[22]);
    acc[23] = fmaf(rad, y3 * z,   acc[23]);
    acc[24] = fmaf(rad, y4,       acc[24]);
    acc[25] = fmaf(rad, x * z3,   acc[25]);
    acc[26] = fmaf(rad, xy * z2,  acc[26]);
    acc[27] = fmaf(rad, x * y2 * z, acc[27]);
    acc[28] = fmaf(rad, x * y3,   acc[28]);
    acc[29] = fmaf(rad, x2 * z2,  acc[29]);
    acc[30] = fmaf(rad, x2 * yz,  acc[30]);
    acc[31] = fmaf(rad, x2 * y2,  acc[31]);
    acc[32] = fmaf(rad, x3 * z,   acc[32]);
    acc[33] = fmaf(rad, x3 * y,   acc[33]);
    acc[34] = fmaf(rad, x4,       acc[34]);
}

// ---------------- wave-parallel lower_bound (64-ary search) ----------------
// Returns first index i in [0,E) with a[i] >= key (E if none).
// Uniform across the wave; ~3 dependent probe rounds for E=1e5.
__device__ __forceinline__ int lb_wave(const int* __restrict__ a, int E,
                                       int key, int lane)
{
    int lo = 0, hi = E;            // invariant: a[<lo] < key, a[>=hi] >= key
    while (hi - lo > 64) {
        const int step = (hi - lo + 63) >> 6;
        const int p = lo + lane * step;
        const int v = (p < hi) ? a[p] : 0x7fffffff;
        const int k = __popcll(__ballot(v < key));   // sorted -> prefix mask
        if (k == 0) return lo;                       // a[lo] >= key
        const int nlo = lo + (k - 1) * step + 1;
        const int nhi = min(lo + k * step, hi);
        lo = nlo; hi = nhi;
    }
    // final round: direct probe of [lo, hi), hi-lo <= 64
    const int p = lo + lane;
    const int v = (p < hi) ? a[p] : 0x7fffffff;
    return lo + __popcll(__ballot(v < key));
}

// ---------------- single fused kernel: ONE WAVE per atom -------------------
// No workspace, no LDS, no barriers, one dispatch. Each lane owns one
// (r, zi) channel; segment bounds found by wave-parallel binary search.
__global__ __launch_bounds__(64) void mbp_fused(
    const float* __restrict__ rij_unit,
    const float* __restrict__ radial_ij,
    const float* __restrict__ lambda_w,
    const float* __restrict__ fact_norm,
    const int*   __restrict__ first_atom,
    float* __restrict__ out,
    int E)
{
    const int n    = blockIdx.x;
    const int lane = threadIdx.x;       // 64-thread block = 1 wave
    const int zi   = lane >> 4;
    const int r    = lane & 15;

    const int start = lb_wave(first_atom, E, n, lane);
    const int end   = lb_wave(first_atom, E, n + 1, lane);

    float acc[NMON];
    #pragma unroll
    for (int l = 0; l < NMON; ++l) acc[l] = 0.f;
    float acc2 = 0.f;

    const int off  = r * NCH + zi;      // three-body channel 0..3
    const int off4 = r * NCH + 4;       // two-body channel

    #pragma unroll 4
    for (int e = start; e < end; ++e) {
        const float* __restrict__ row = radial_ij + (size_t)e * ROWF;
        const float rad = row[off];
        const float c4  = row[off4];
        const float x   = rij_unit[3 * e + 0];
        const float y   = rij_unit[3 * e + 1];
        const float z   = rij_unit[3 * e + 2];
        edge_body(x, y, z, rad, c4, acc, acc2);
    }

    // ---------------- lane-local epilogue ----------------
    const float l0 = lambda_w[0], l1 = lambda_w[1];
    const float p0[5] = {1.f, l0, l0 * l0, l0 * l0 * l0, (l0 * l0) * (l0 * l0)};
    const float p1[5] = {1.f, l1, l1 * l1, l1 * l1 * l1, (l1 * l1) * (l1 * l1)};
    const int lsum_tab[NMON] = {0, 1,1,1, 2,2,2,2,2,2,
                                3,3,3,3,3,3,3,3,3,3,
                                4,4,4,4,4,4,4,4,4,4,4,4,4,4,4};
    float s0 = 0.f, s1 = 0.f;
    #pragma unroll
    for (int l = 0; l < NMON; ++l) {
        const float v  = acc[l] * fact_norm[l];
        const float v2 = v * v;
        s0 = fmaf(v2, p0[lsum_tab[l]], s0);
        s1 = fmaf(v2, p1[lsum_tab[l]], s1);
    }
    const float scale = 1.0f / (float)(1 << zi);   // 2^(1-zeta), zeta = zi+1
    float* orow = out + (long)n * OUTW;
    orow[16 + zi * 32 + r * 2 + 0] = s0 * scale;
    orow[16 + zi * 32 + r * 2 + 1] = s1 * scale;
    if (zi == 0) orow[r] = acc2;
}

extern "C" void kernel_launch(void* const* d_in, const int* in_sizes, int n_in,
                              void* d_out, int out_size, void* d_ws, size_t ws_size,
                              hipStream_t stream) {
    const float* rij_unit   = (const float*)d_in[0];
    const float* radial_ij  = (const float*)d_in[1];
    const float* lambda_w   = (const float*)d_in[2];
    const float* fact_norm  = (const float*)d_in[3];
    const int*   first_atom = (const int*)d_in[4];
    const int E   = in_sizes[4];
    const int nat = out_size / OUTW;

    mbp_fused<<<nat, 64, 0, stream>>>(rij_unit, radial_ij, lambda_w,
                                      fact_norm, first_atom, (float*)d_out, E);
}